// Round 1
// baseline (364.239 us; speedup 1.0000x reference)
//
#include <hip/hip_runtime.h>
#include <math.h>

// d: (262144, 256) float32, row-major. Compute s[j] = sum_i d[i][j]^2,
// out = 0.001 * sqrt(sum_j (s[j]-1)^2).  Memory-bound: 256 MiB stream.

#define NROW   262144
#define NCOL   256
#define NCOLV  64        // columns in float4 units
#define GRID   2048      // 8 blocks/CU on 256 CUs
#define ITERS  (NROW / 4 / GRID)   // 32 four-row groups per block

__global__ __launch_bounds__(256) void colsq_kernel(
        const float4* __restrict__ d, float* __restrict__ g_col) {
    const int tid   = threadIdx.x;
    const int c4    = tid & 63;   // float4 column index 0..63
    const int r_off = tid >> 6;   // row within 4-row group, 0..3

    float4 acc = make_float4(0.f, 0.f, 0.f, 0.f);

    // Each block streams a contiguous 128 KiB chunk: rows
    // [blockIdx*128, blockIdx*128 + 128). One iteration = 4 rows = 4 KiB,
    // wave-contiguous dwordx4 loads.
    const size_t base_rg = (size_t)blockIdx.x * ITERS;
#pragma unroll 4
    for (int i = 0; i < ITERS; ++i) {
        const size_t row = (base_rg + i) * 4 + r_off;
        const float4 v = d[row * NCOLV + c4];
        acc.x += v.x * v.x;
        acc.y += v.y * v.y;
        acc.z += v.z * v.z;
        acc.w += v.w * v.w;
    }

    // Block reduce across the 4 r_off groups via LDS.
    __shared__ float lds[4 * NCOL];
    float4* l4 = (float4*)lds;
    l4[r_off * NCOLV + c4] = acc;          // contiguous b128 per wave
    __syncthreads();
    // thread t owns column t
    float s = lds[tid] + lds[NCOL + tid] + lds[2 * NCOL + tid] + lds[3 * NCOL + tid];
    atomicAdd(&g_col[tid], s);
}

__global__ __launch_bounds__(256) void finalize_kernel(
        const float* __restrict__ g_col, float* __restrict__ out) {
    const int tid = threadIdx.x;
    float diff = g_col[tid] - 1.0f;
    float v = diff * diff;
    // wave (64-lane) butterfly reduce
#pragma unroll
    for (int off = 32; off > 0; off >>= 1)
        v += __shfl_down(v, off, 64);
    __shared__ float ws[4];
    if ((tid & 63) == 0) ws[tid >> 6] = v;
    __syncthreads();
    if (tid == 0) {
        float t = ws[0] + ws[1] + ws[2] + ws[3];
        out[0] = 0.001f * sqrtf(t);
    }
}

extern "C" void kernel_launch(void* const* d_in, const int* in_sizes, int n_in,
                              void* d_out, int out_size, void* d_ws, size_t ws_size,
                              hipStream_t stream) {
    const float4* d  = (const float4*)d_in[0];
    float* g_col     = (float*)d_ws;    // 256 floats of scratch
    float* out       = (float*)d_out;

    hipMemsetAsync(g_col, 0, NCOL * sizeof(float), stream);
    colsq_kernel<<<GRID, 256, 0, stream>>>(d, g_col);
    finalize_kernel<<<1, 256, 0, stream>>>(g_col, out);
}